// Round 14
// baseline (147.223 us; speedup 1.0000x reference)
//
#include <hip/hip_runtime.h>
#include <math.h>

#define NBINS 80
#define NVERT 128
#define NRH 5
#define NDEG 6           // Taylor terms d=0..5; remainder ~1e-5 (<< f16 eps)

#define PSTR 136         // halves per P/M row; cols 0..127 data, 128..135 pad
#define VSTR2 66         // halves per VT2 row (132 B = 33 words, coprime w/ 32 banks)
#define DSTR 80          // halves per desc row

#define OFF_VT 6800      // P/M: 25*136*2 = 6800 B at [0,6800)
#define OFF_GM 19472     // VT2: 96*66*2 = 12672 B at [6800,19472)
#define SLICE  19728     // gm: 256 B at [19472,19728); desc overlays [0,10240)

#define NSET_C 48        // C-matrix frag sets: 16 nt x 3 ks
#define NSET_W 60        // W frag sets: 4 i x 5 tiles x 3 ks
#define WS_BYTES ((NSET_C + NSET_W) * 64 * 8 * 2)

typedef _Float16 half8 __attribute__((ext_vector_type(8)));
typedef float f32x4 __attribute__((ext_vector_type(4)));

// ---- prep: constant C-matrix frags + W frags in d_ws ----
// C[(a,d)][(nt,t)] = exp2(Kt*s^2) * z^d/d!,  s=(((a+nt)&15)-t)*DLT + DLT/2,
// z = 2*ln2*Kt*s*(DLT/2); pairs with V[c][(a,d)] = gam_c * u_c^d.
__global__ __launch_bounds__(64) void prep_frags(const float* __restrict__ Wc,
                                                 const float* __restrict__ sig_th,
                                                 _Float16* __restrict__ ws) {
    const int blk  = blockIdx.x;
    const int lane = threadIdx.x;
    constexpr float TWO_PI = 6.28318530717958647692f;
    constexpr float DLT    = TWO_PI / 16.0f;
    constexpr float LN2    = 0.69314718055994530942f;
    half8 h;
    if (blk < NSET_C) {
        constexpr float LOG2E = 1.44269504088896340736f;
        constexpr float EPSF  = 1e-5f;
        const float st = sig_th[0];
        const float Kt = -LOG2E / (st * st + EPSF);
        const int ks = blk % 3;
        const int nt = blk / 3;
        const int t  = lane & 15;
        const int q  = lane >> 4;
        #pragma unroll
        for (int j = 0; j < 8; ++j) {
            const int k = ks * 32 + q * 8 + j;     // 0..95
            const int a = k / NDEG;
            const int d = k % NDEG;
            const int m = ((a + nt) & 15) - t;
            const float s = fmaf((float)m, DLT, 0.5f * DLT);
            const float z = 2.0f * LN2 * Kt * s * (0.5f * DLT);
            float val = exp2f(Kt * s * s);
            for (int dd = 1; dd <= d; ++dd) val *= z / (float)dd;
            h[j] = (_Float16)val;
        }
    } else {
        const int e    = blk - NSET_C;
        const int ks   = e % 3;
        const int tile = (e / 3) % 5;
        const int i    = e / 15;
        const int cc   = tile * 16 + (lane & 15);
        const int bb0  = ks * 32 + (lane >> 4) * 8;
        #pragma unroll
        for (int j = 0; j < 8; ++j) {
            const int bb = bb0 + j;
            h[j] = (_Float16)((bb < NBINS) ? Wc[i * NBINS * NBINS + bb * NBINS + cc] : 0.0f);
        }
    }
    *(half8*)(ws + ((size_t)blk * 64 + lane) * 8) = h;
}

// Single-wave blocks (R10-verified body). R13 changes ONLY:
//  (1) compaction global loads hoisted (one HBM-latency exposure, not two);
//  (2) chain1 in 64-vertex super-chunks: ONE VT build+drain per 64 c (2 total
//      instead of 4); VT2 row stride 66 halves breaks pow2 bank aliasing.
// R9 lesson: no persistent loop. R12 lesson: no multi-sample register doubling.
__global__ __launch_bounds__(64) void masif_geo_conv(
    const float* __restrict__ rho_c,
    const float* __restrict__ th_c,
    const float* __restrict__ feat_g,
    const float* __restrict__ mask_g,
    const float* __restrict__ mu_rho,
    const float* __restrict__ sig_rho,
    const float* __restrict__ mu_th,
    const float* __restrict__ sig_th,
    const float* __restrict__ Wc,
    const float* __restrict__ bcv,
    const _Float16* __restrict__ ws,
    const int useWs,
    const int nsamp,
    float* __restrict__ out)
{
    const int lane = threadIdx.x;
    const int n    = blockIdx.x;
    if (n >= nsamp) return;

    const int t  = lane & 15;
    const int kq = lane >> 4;

    __shared__ __align__(16) char s_raw[SLICE];
    _Float16* s_PM = (_Float16*)(s_raw);            // P (A) / M (B) / desc overlay
    _Float16* s_vt = (_Float16*)(s_raw + OFF_VT);   // VT2: 96 rows x 66 halves
    _Float16* s_gm = (_Float16*)(s_raw + OFF_GM);
    _Float16* s_d  = (_Float16*)(s_raw);

    constexpr float LOG2E   = 1.44269504088896340736f;
    constexpr float TWO_PI  = 6.28318530717958647692f;
    constexpr float DLT     = TWO_PI / 16.0f;
    constexpr float INV_DLT = 16.0f / TWO_PI;
    constexpr float EPSF    = 1e-5f;

    const float st = sig_th[0];
    const float Kt = -LOG2E / (st * st + EPSF);
    const float sr = sig_rho[0];
    const float Kr = -LOG2E / (sr * sr + EPSF);
    float mr[NRH];
    #pragma unroll
    for (int r = 0; r < NRH; ++r) mr[r] = mu_rho[r * 16];

    // ---- zero P incl. pads (25*136 halves = 425 int4) ----
    #pragma unroll
    for (int x = 0; x < 7; ++x) {
        const int idx = x * 64 + lane;
        if (idx < 425) ((int4*)s_PM)[idx] = make_int4(0, 0, 0, 0);
    }

    // ---- compaction with hoisted loads: all 8 global loads issued up front ----
    float  mv[2], thv[2], rhov[2];
    float4 fv4[2];
    #pragma unroll
    for (int rr = 0; rr < 2; ++rr) {
        const int v = rr * 64 + lane;
        mv[rr]   = mask_g[n * NVERT + v];
        thv[rr]  = th_c[n * NVERT + v];
        rhov[rr] = rho_c[n * NVERT + v];
        fv4[rr]  = *(const float4*)&feat_g[(n * NVERT + v) * 4];
    }
    // P rows: (f,r<4)->f*4+r ; (f,r=4)->16+f ; den r->20+r.
    // Tails in P col-pad: u f16 rows 0..15 cols 128..135; a u8 rows 16..23.
    int cbase = 0;
    #pragma unroll
    for (int rr = 0; rr < 2; ++rr) {
        const float m = mv[rr];
        const bool act = (m != 0.0f);
        const unsigned long long bal = __ballot(act);
        if (act) {
            const int pos = cbase + (int)__popcll(bal & ((1ull << lane) - 1ull));
            const float th0 = thv[rr];
            const float rho = rhov[rr];
            int aa = (int)floorf(th0 * INV_DLT);
            aa = aa > 15 ? 15 : (aa < 0 ? 0 : aa);
            const float rvp = th0 - (float)aa * DLT - 0.5f * DLT;   // [-DLT/2, DLT/2)
            float R[NRH];
            #pragma unroll
            for (int r = 0; r < NRH; ++r) {
                const float dr = rho - mr[r];
                R[r] = m * exp2f(Kr * dr * dr);
            }
            const float fv[4] = {fv4[rr].x, fv4[rr].y, fv4[rr].z, fv4[rr].w};
            #pragma unroll
            for (int f = 0; f < 4; ++f) {
                #pragma unroll
                for (int r = 0; r < 4; ++r)
                    s_PM[(f * 4 + r) * PSTR + pos] = (_Float16)(fv[f] * R[r]);
                s_PM[(16 + f) * PSTR + pos] = (_Float16)(fv[f] * R[4]);
            }
            #pragma unroll
            for (int r = 0; r < NRH; ++r)
                s_PM[(20 + r) * PSTR + pos] = (_Float16)R[r];
            s_PM[(pos >> 3) * PSTR + 128 + (pos & 7)] = (_Float16)(rvp * (2.0f * INV_DLT));
            ((char*)s_PM)[(16 + (pos >> 4)) * 2 * PSTR + 256 + (pos & 15)] = (char)aa;
            s_gm[pos] = (_Float16)exp2f(Kt * rvp * rvp);
        }
        cbase += (int)__popcll(bal);
    }
    const int nc = cbase;   // wave-uniform

    // ---- chain 1: M[25x96] = P[25x128c] @ V[128c x 96(a,d)], SUPER-chunks of 64 ----
    f32x4 M0[NDEG], M1[NDEG];
    #pragma unroll
    for (int ct = 0; ct < NDEG; ++ct) {
        M0[ct] = (f32x4){0.f, 0.f, 0.f, 0.f};
        M1[ct] = (f32x4){0.f, 0.f, 0.f, 0.f};
    }
    const int nsc = (nc + 63) >> 6;    // 1 or 2
    for (int sc = 0; sc < nsc; ++sc) {
        // zero VT2 (12672 B = 792 int4)
        #pragma unroll
        for (int x = 0; x < 13; ++x) {
            const int idx = x * 64 + lane;
            if (idx < 792) ((int4*)s_vt)[idx] = make_int4(0, 0, 0, 0);
        }
        // build: ONE vertex per lane, all 6 Taylor rows (single drain per sc)
        {
            const int cg = sc * 64 + lane;
            if (cg < nc) {
                const float u = (float)s_PM[(cg >> 3) * PSTR + 128 + (cg & 7)];
                const float g = (float)s_gm[cg];
                const int   a = (int)((char*)s_PM)[(16 + (cg >> 4)) * 2 * PSTR + 256 + (cg & 15)];
                const int base = a * NDEG * VSTR2 + lane;
                float p = g;
                #pragma unroll
                for (int d = 0; d < NDEG; ++d) {
                    s_vt[base + d * VSTR2] = (_Float16)p;   // V[c][(a,d)] = gam*u^d
                    p *= u;
                }
            }
        }
        // two 32-column MFMA halves off one build
        #pragma unroll
        for (int h = 0; h < 2; ++h) {
            const int c0 = sc * 64 + h * 32;
            // A-frags; t>8 on tile1 reads rows 25..31 (finite garbage -> unread M1 rows)
            const half8 a0 = *(const half8*)(s_PM + t * PSTR + c0 + kq * 8);
            const half8 a1 = *(const half8*)(s_PM + (16 + t) * PSTR + c0 + kq * 8);
            #pragma unroll
            for (int ct = 0; ct < NDEG; ++ct) {
                const half8 b = *(const half8*)(s_vt + (ct * 16 + t) * VSTR2 + h * 32 + kq * 8);
                M0[ct] = __builtin_amdgcn_mfma_f32_16x16x32_f16(a0, b, M0[ct], 0, 0, 0);
                M1[ct] = __builtin_amdgcn_mfma_f32_16x16x32_f16(a1, b, M1[ct], 0, 0, 0);
            }
        }
    }

    // ---- M -> LDS f16 A-layout (overlays P). D: col=t, row=kq*4+reg ----
    #pragma unroll
    for (int ct = 0; ct < NDEG; ++ct) {
        const int md = ct * 16 + t;
        #pragma unroll
        for (int reg = 0; reg < 4; ++reg) {
            s_PM[(kq * 4 + reg) * PSTR + md] = (_Float16)M0[ct][reg];
            if (kq * 4 + reg < 9)
                s_PM[(16 + kq * 4 + reg) * PSTR + md] = (_Float16)M1[ct][reg];
        }
    }

    // ---- chain2 A-frags -> regs (24 VGPRs); M LDS region dies here ----
    half8 A0[3], A1[3];
    #pragma unroll
    for (int ks = 0; ks < 3; ++ks) {
        A0[ks] = *(const half8*)(s_PM + t * PSTR + ks * 32 + kq * 8);
        A1[ks] = *(const half8*)(s_PM + (16 + t) * PSTR + ks * 32 + kq * 8);
    }

    // ---- chain 2 in nt-groups of 4 with fused epilogue (32 live acc regs) ----
    const half8* wsv = (const half8*)ws;
    #pragma unroll
    for (int g = 0; g < 4; ++g) {
        f32x4 C0g[4], C1g[4];
        #pragma unroll
        for (int j = 0; j < 4; ++j) {
            C0g[j] = (f32x4){0.f, 0.f, 0.f, 0.f};
            C1g[j] = (f32x4){0.f, 0.f, 0.f, 0.f};
        }
        #pragma unroll
        for (int j = 0; j < 4; ++j) {
            const int nt = g * 4 + j;
            half8 b0, b1, b2;
            if (useWs) {
                b0 = wsv[(size_t)((nt * 3 + 0) * 64 + lane)];
                b1 = wsv[(size_t)((nt * 3 + 1) * 64 + lane)];
                b2 = wsv[(size_t)((nt * 3 + 2) * 64 + lane)];
            } else {
                #pragma unroll
                for (int ks = 0; ks < 3; ++ks) {
                    half8 bb;
                    #pragma unroll
                    for (int jj = 0; jj < 8; ++jj) {
                        const int k = ks * 32 + kq * 8 + jj;
                        const int a = k / NDEG, d = k % NDEG;
                        const int mm = ((a + nt) & 15) - t;
                        const float s = fmaf((float)mm, DLT, 0.5f * DLT);
                        const float z = 2.0f * 0.69314718055994530942f * Kt * s * (0.5f * DLT);
                        float val = exp2f(Kt * s * s);
                        for (int dd = 1; dd <= d; ++dd) val *= z / (float)dd;
                        bb[jj] = (_Float16)val;
                    }
                    if (ks == 0) b0 = bb; else if (ks == 1) b1 = bb; else b2 = bb;
                }
            }
            C0g[j] = __builtin_amdgcn_mfma_f32_16x16x32_f16(A0[0], b0, C0g[j], 0, 0, 0);
            C1g[j] = __builtin_amdgcn_mfma_f32_16x16x32_f16(A1[0], b0, C1g[j], 0, 0, 0);
            C0g[j] = __builtin_amdgcn_mfma_f32_16x16x32_f16(A0[1], b1, C0g[j], 0, 0, 0);
            C1g[j] = __builtin_amdgcn_mfma_f32_16x16x32_f16(A1[1], b1, C1g[j], 0, 0, 0);
            C0g[j] = __builtin_amdgcn_mfma_f32_16x16x32_f16(A0[2], b2, C0g[j], 0, 0, 0);
            C1g[j] = __builtin_amdgcn_mfma_f32_16x16x32_f16(A1[2], b2, C1g[j], 0, 0, 0);
        }
        // fused epilogue (R5-verified): desc = num/(den+eps) -> s_d[i][k][bb]
        #pragma unroll
        for (int j = 0; j < 4; ++j) {
            const int nt = g * 4 + j;
            float den[5], inv[5];
            #pragma unroll
            for (int r = 0; r < 4; ++r) den[r] = __shfl(C1g[j][r], 16 + t);
            den[4] = __shfl(C1g[j][0], 32 + t);
            #pragma unroll
            for (int r = 0; r < NRH; ++r) {
                const float x = den[r] + EPSF;
                float vv = __builtin_amdgcn_rcpf(x);
                inv[r] = vv * (2.0f - x * vv);
            }
            #pragma unroll
            for (int reg = 0; reg < 4; ++reg)
                s_d[kq * 1280 + nt * DSTR + reg * 16 + t] =
                    (_Float16)(C0g[j][reg] * inv[reg]);
            if (kq == 0) {
                #pragma unroll
                for (int reg = 0; reg < 4; ++reg)
                    s_d[reg * 1280 + nt * DSTR + 64 + t] =
                        (_Float16)(C1g[j][reg] * inv[4]);
            }
        }
    }

    // ---- phase 2 (R4/R5-verified): per i, conv = desc @ W_i, max over k ----
    #pragma unroll
    for (int i = 0; i < 4; ++i) {
        f32x4 Cc[5];
        #pragma unroll
        for (int tile = 0; tile < 5; ++tile) Cc[tile] = (f32x4){0.f, 0.f, 0.f, 0.f};
        #pragma unroll
        for (int ks = 0; ks < 3; ++ks) {
            const half8 a = *(const half8*)(s_d + i * 1280 + t * DSTR + ks * 32 + kq * 8);
            #pragma unroll
            for (int tile = 0; tile < 5; ++tile) {
                half8 b;
                if (useWs) {
                    b = wsv[(size_t)((NSET_C + (i * 5 + tile) * 3 + ks) * 64 + lane)];
                } else {
                    const int cc  = tile * 16 + t;
                    const int bb0 = ks * 32 + kq * 8;
                    #pragma unroll
                    for (int j = 0; j < 8; ++j) {
                        const int bb = bb0 + j;
                        b[j] = (_Float16)((bb < NBINS) ? Wc[i * NBINS * NBINS + bb * NBINS + cc] : 0.0f);
                    }
                }
                Cc[tile] = __builtin_amdgcn_mfma_f32_16x16x32_f16(a, b, Cc[tile], 0, 0, 0);
            }
        }
        #pragma unroll
        for (int tile = 0; tile < 5; ++tile) {
            float m = fmaxf(fmaxf(Cc[tile][0], Cc[tile][1]), fmaxf(Cc[tile][2], Cc[tile][3]));
            m = fmaxf(m, __shfl_xor(m, 16));
            m = fmaxf(m, __shfl_xor(m, 32));
            if (lane < 16) {
                const int cc = tile * 16 + lane;
                out[(size_t)n * 320 + i * NBINS + cc] =
                    fmaxf(m + bcv[i * NBINS + cc], 0.0f);
            }
        }
    }
}

extern "C" void kernel_launch(void* const* d_in, const int* in_sizes, int n_in,
                              void* d_out, int out_size, void* d_ws, size_t ws_size,
                              hipStream_t stream) {
    const float* rho   = (const float*)d_in[0];
    const float* theta = (const float*)d_in[1];
    const float* feat  = (const float*)d_in[2];
    const float* mask  = (const float*)d_in[3];
    const float* mu_r  = (const float*)d_in[4];
    const float* sg_r  = (const float*)d_in[5];
    const float* mu_t  = (const float*)d_in[6];
    const float* sg_t  = (const float*)d_in[7];
    const float* W     = (const float*)d_in[8];
    const float* bconv = (const float*)d_in[9];
    float* outp = (float*)d_out;

    const int nsamp = in_sizes[0] / NVERT;
    const int useWs = (ws_size >= (size_t)WS_BYTES) ? 1 : 0;
    _Float16* wsh = (_Float16*)d_ws;

    if (useWs) prep_frags<<<NSET_C + NSET_W, 64, 0, stream>>>(W, sg_t, wsh);

    masif_geo_conv<<<nsamp, 64, 0, stream>>>(
        rho, theta, feat, mask, mu_r, sg_r, mu_t, sg_t, W, bconv,
        wsh, useWs, nsamp, outp);
}

// Round 15
// 140.999 us; speedup vs baseline: 1.0441x; 1.0441x over previous
//
#include <hip/hip_runtime.h>
#include <math.h>

#define NBINS 80
#define NVERT 128
#define NRH 5
#define NDEG 6           // Taylor terms d=0..5; remainder ~1e-5 (<< f16 eps)

#define PSTR 136         // halves per P/M row; cols 0..127 data, 128..135 pad
#define VSTR 40          // halves per VT row (80 B = 20 words: 16B-aligned b128,
                         // 20*r mod 32 period-8 -> 2-way banks = free; 32 was 8-way)
#define DSTR 80          // halves per desc row

#define OFF_VT 6800      // P/M: 25*136*2 = 6800 B at [0,6800)
#define OFF_GM 14480     // VT: 96*40*2 = 7680 B at [6800,14480)
#define SLICE  14736     // gm: 256 B; desc overlays [0,10240) after chain1

#define NSET_C 48        // C-matrix frag sets: 16 nt x 3 ks
#define NSET_W 60        // W frag sets: 4 i x 5 tiles x 3 ks
#define WS_BYTES ((NSET_C + NSET_W) * 64 * 8 * 2)

typedef _Float16 half8 __attribute__((ext_vector_type(8)));
typedef float f32x4 __attribute__((ext_vector_type(4)));

// ---- prep: constant C-matrix frags + W frags in d_ws ----
// C[(a,d)][(nt,t)] = exp2(Kt*s^2) * z^d/d!,  s=(((a+nt)&15)-t)*DLT + DLT/2,
// z = 2*ln2*Kt*s*(DLT/2); pairs with V[c][(a,d)] = gam_c * u_c^d.
__global__ __launch_bounds__(64) void prep_frags(const float* __restrict__ Wc,
                                                 const float* __restrict__ sig_th,
                                                 _Float16* __restrict__ ws) {
    const int blk  = blockIdx.x;
    const int lane = threadIdx.x;
    constexpr float TWO_PI = 6.28318530717958647692f;
    constexpr float DLT    = TWO_PI / 16.0f;
    constexpr float LN2    = 0.69314718055994530942f;
    half8 h;
    if (blk < NSET_C) {
        constexpr float LOG2E = 1.44269504088896340736f;
        constexpr float EPSF  = 1e-5f;
        const float st = sig_th[0];
        const float Kt = -LOG2E / (st * st + EPSF);
        const int ks = blk % 3;
        const int nt = blk / 3;
        const int t  = lane & 15;
        const int q  = lane >> 4;
        #pragma unroll
        for (int j = 0; j < 8; ++j) {
            const int k = ks * 32 + q * 8 + j;     // 0..95
            const int a = k / NDEG;
            const int d = k % NDEG;
            const int m = ((a + nt) & 15) - t;
            const float s = fmaf((float)m, DLT, 0.5f * DLT);
            const float z = 2.0f * LN2 * Kt * s * (0.5f * DLT);
            float val = exp2f(Kt * s * s);
            for (int dd = 1; dd <= d; ++dd) val *= z / (float)dd;
            h[j] = (_Float16)val;
        }
    } else {
        const int e    = blk - NSET_C;
        const int ks   = e % 3;
        const int tile = (e / 3) % 5;
        const int i    = e / 15;
        const int cc   = tile * 16 + (lane & 15);
        const int bb0  = ks * 32 + (lane >> 4) * 8;
        #pragma unroll
        for (int j = 0; j < 8; ++j) {
            const int bb = bb0 + j;
            h[j] = (_Float16)((bb < NBINS) ? Wc[i * NBINS * NBINS + bb * NBINS + cc] : 0.0f);
        }
    }
    *(half8*)(ws + ((size_t)blk * 64 + lane) * 8) = h;
}

// R10-verified body. R14 deltas ONLY: (1) VT row stride 32->40 halves (kills
// the 8-way bank aliasing measured as 1.24M conflict cycles); (2) compaction
// global loads hoisted (one HBM-latency exposure). R9: no persistent loop.
// R12: no multi-sample register doubling. R7: keep total VGPR+AGPR modest.
__global__ __launch_bounds__(64) void masif_geo_conv(
    const float* __restrict__ rho_c,
    const float* __restrict__ th_c,
    const float* __restrict__ feat_g,
    const float* __restrict__ mask_g,
    const float* __restrict__ mu_rho,
    const float* __restrict__ sig_rho,
    const float* __restrict__ mu_th,
    const float* __restrict__ sig_th,
    const float* __restrict__ Wc,
    const float* __restrict__ bcv,
    const _Float16* __restrict__ ws,
    const int useWs,
    const int nsamp,
    float* __restrict__ out)
{
    const int lane = threadIdx.x;
    const int n    = blockIdx.x;
    if (n >= nsamp) return;

    const int t  = lane & 15;
    const int kq = lane >> 4;

    __shared__ __align__(16) char s_raw[SLICE];
    _Float16* s_PM = (_Float16*)(s_raw);            // P (A) / M (B) / desc overlay
    _Float16* s_vt = (_Float16*)(s_raw + OFF_VT);   // VT: 96 rows x 40 halves
    _Float16* s_gm = (_Float16*)(s_raw + OFF_GM);
    _Float16* s_d  = (_Float16*)(s_raw);

    constexpr float LOG2E   = 1.44269504088896340736f;
    constexpr float TWO_PI  = 6.28318530717958647692f;
    constexpr float DLT     = TWO_PI / 16.0f;
    constexpr float INV_DLT = 16.0f / TWO_PI;
    constexpr float EPSF    = 1e-5f;

    const float st = sig_th[0];
    const float Kt = -LOG2E / (st * st + EPSF);
    const float sr = sig_rho[0];
    const float Kr = -LOG2E / (sr * sr + EPSF);
    float mr[NRH];
    #pragma unroll
    for (int r = 0; r < NRH; ++r) mr[r] = mu_rho[r * 16];

    // ---- zero P incl. pads (25*136 halves = 425 int4) ----
    #pragma unroll
    for (int x = 0; x < 7; ++x) {
        const int idx = x * 64 + lane;
        if (idx < 425) ((int4*)s_PM)[idx] = make_int4(0, 0, 0, 0);
    }

    // ---- compaction, all 8 global loads hoisted up front ----
    float  mv[2], thv[2], rhov[2];
    float4 fvv[2];
    #pragma unroll
    for (int rr = 0; rr < 2; ++rr) {
        const int v = rr * 64 + lane;
        mv[rr]   = mask_g[n * NVERT + v];
        thv[rr]  = th_c[n * NVERT + v];
        rhov[rr] = rho_c[n * NVERT + v];
        fvv[rr]  = *(const float4*)&feat_g[(n * NVERT + v) * 4];
    }
    // P rows: (f,r<4)->f*4+r ; (f,r=4)->16+f ; den r->20+r.
    // Tails in P col-pad: u f16 rows 0..15 cols 128..135; a u8 rows 16..23.
    int cbase = 0;
    #pragma unroll
    for (int rr = 0; rr < 2; ++rr) {
        const float m = mv[rr];
        const bool act = (m != 0.0f);
        const unsigned long long bal = __ballot(act);
        if (act) {
            const int pos = cbase + (int)__popcll(bal & ((1ull << lane) - 1ull));
            const float th0 = thv[rr];
            const float rho = rhov[rr];
            int aa = (int)floorf(th0 * INV_DLT);
            aa = aa > 15 ? 15 : (aa < 0 ? 0 : aa);
            const float rvp = th0 - (float)aa * DLT - 0.5f * DLT;   // [-DLT/2, DLT/2)
            float R[NRH];
            #pragma unroll
            for (int r = 0; r < NRH; ++r) {
                const float dr = rho - mr[r];
                R[r] = m * exp2f(Kr * dr * dr);
            }
            const float fv[4] = {fvv[rr].x, fvv[rr].y, fvv[rr].z, fvv[rr].w};
            #pragma unroll
            for (int f = 0; f < 4; ++f) {
                #pragma unroll
                for (int r = 0; r < 4; ++r)
                    s_PM[(f * 4 + r) * PSTR + pos] = (_Float16)(fv[f] * R[r]);
                s_PM[(16 + f) * PSTR + pos] = (_Float16)(fv[f] * R[4]);
            }
            #pragma unroll
            for (int r = 0; r < NRH; ++r)
                s_PM[(20 + r) * PSTR + pos] = (_Float16)R[r];
            s_PM[(pos >> 3) * PSTR + 128 + (pos & 7)] = (_Float16)(rvp * (2.0f * INV_DLT));
            ((char*)s_PM)[(16 + (pos >> 4)) * 2 * PSTR + 256 + (pos & 15)] = (char)aa;
            s_gm[pos] = (_Float16)exp2f(Kt * rvp * rvp);
        }
        cbase += (int)__popcll(bal);
    }
    const int nc = cbase;   // wave-uniform

    // ---- chain 1: M[25x96] = P[25x128c] @ V[128c x 96(a,d)], chunks of 32 ----
    f32x4 M0[NDEG], M1[NDEG];
    #pragma unroll
    for (int ct = 0; ct < NDEG; ++ct) {
        M0[ct] = (f32x4){0.f, 0.f, 0.f, 0.f};
        M1[ct] = (f32x4){0.f, 0.f, 0.f, 0.f};
    }
    const int nch = (nc + 31) >> 5;
    for (int ch = 0; ch < nch; ++ch) {
        // zero VT (96 rows x 40 halves = 7680 B = 480 int4)
        #pragma unroll
        for (int x = 0; x < 8; ++x) {
            const int idx = x * 64 + lane;
            if (idx < 480) ((int4*)s_vt)[idx] = make_int4(0, 0, 0, 0);
        }
        // build: lane -> (cl = lane>>1, d-half = (lane&1)*3); cols = chunk's 32 c
        {
            const int cl = lane >> 1;
            const int cg = ch * 32 + cl;
            if (cg < nc) {
                const float u = (float)s_PM[(cg >> 3) * PSTR + 128 + (cg & 7)];
                const float g = (float)s_gm[cg];
                const int   a = (int)((char*)s_PM)[(16 + (cg >> 4)) * 2 * PSTR + 256 + (cg & 15)];
                const int  dh = (lane & 1) * 3;
                float p0, p1, p2;
                if (dh == 0) { p0 = 1.0f; p1 = u; p2 = u * u; }
                else { const float u2 = u * u; p0 = u2 * u; p1 = u2 * u2; p2 = p0 * u2; }
                const int bi = (a * NDEG + dh) * VSTR + cl;
                s_vt[bi]            = (_Float16)(g * p0);
                s_vt[bi + VSTR]     = (_Float16)(g * p1);
                s_vt[bi + 2 * VSTR] = (_Float16)(g * p2);
            }
        }
        // A-frags; t>8 on tile1 reads rows 25..31 (benign -> unread M1 rows)
        const half8 a0 = *(const half8*)(s_PM + t * PSTR + ch * 32 + kq * 8);
        const half8 a1 = *(const half8*)(s_PM + (16 + t) * PSTR + ch * 32 + kq * 8);
        #pragma unroll
        for (int ct = 0; ct < NDEG; ++ct) {
            const half8 b = *(const half8*)(s_vt + (ct * 16 + t) * VSTR + kq * 8);
            M0[ct] = __builtin_amdgcn_mfma_f32_16x16x32_f16(a0, b, M0[ct], 0, 0, 0);
            M1[ct] = __builtin_amdgcn_mfma_f32_16x16x32_f16(a1, b, M1[ct], 0, 0, 0);
        }
    }

    // ---- M -> LDS f16 A-layout (overlays P). D: col=t, row=kq*4+reg ----
    #pragma unroll
    for (int ct = 0; ct < NDEG; ++ct) {
        const int md = ct * 16 + t;
        #pragma unroll
        for (int reg = 0; reg < 4; ++reg) {
            s_PM[(kq * 4 + reg) * PSTR + md] = (_Float16)M0[ct][reg];
            if (kq * 4 + reg < 9)
                s_PM[(16 + kq * 4 + reg) * PSTR + md] = (_Float16)M1[ct][reg];
        }
    }

    // ---- chain2 A-frags -> regs (24 VGPRs); M LDS region dies here ----
    half8 A0[3], A1[3];
    #pragma unroll
    for (int ks = 0; ks < 3; ++ks) {
        A0[ks] = *(const half8*)(s_PM + t * PSTR + ks * 32 + kq * 8);
        A1[ks] = *(const half8*)(s_PM + (16 + t) * PSTR + ks * 32 + kq * 8);
    }

    // ---- chain 2 in nt-groups of 4 with fused epilogue (32 live acc regs) ----
    const half8* wsv = (const half8*)ws;
    #pragma unroll
    for (int g = 0; g < 4; ++g) {
        f32x4 C0g[4], C1g[4];
        #pragma unroll
        for (int j = 0; j < 4; ++j) {
            C0g[j] = (f32x4){0.f, 0.f, 0.f, 0.f};
            C1g[j] = (f32x4){0.f, 0.f, 0.f, 0.f};
        }
        #pragma unroll
        for (int j = 0; j < 4; ++j) {
            const int nt = g * 4 + j;
            half8 b0, b1, b2;
            if (useWs) {
                b0 = wsv[(size_t)((nt * 3 + 0) * 64 + lane)];
                b1 = wsv[(size_t)((nt * 3 + 1) * 64 + lane)];
                b2 = wsv[(size_t)((nt * 3 + 2) * 64 + lane)];
            } else {
                #pragma unroll
                for (int ks = 0; ks < 3; ++ks) {
                    half8 bb;
                    #pragma unroll
                    for (int jj = 0; jj < 8; ++jj) {
                        const int k = ks * 32 + kq * 8 + jj;
                        const int a = k / NDEG, d = k % NDEG;
                        const int mm = ((a + nt) & 15) - t;
                        const float s = fmaf((float)mm, DLT, 0.5f * DLT);
                        const float z = 2.0f * 0.69314718055994530942f * Kt * s * (0.5f * DLT);
                        float val = exp2f(Kt * s * s);
                        for (int dd = 1; dd <= d; ++dd) val *= z / (float)dd;
                        bb[jj] = (_Float16)val;
                    }
                    if (ks == 0) b0 = bb; else if (ks == 1) b1 = bb; else b2 = bb;
                }
            }
            C0g[j] = __builtin_amdgcn_mfma_f32_16x16x32_f16(A0[0], b0, C0g[j], 0, 0, 0);
            C1g[j] = __builtin_amdgcn_mfma_f32_16x16x32_f16(A1[0], b0, C1g[j], 0, 0, 0);
            C0g[j] = __builtin_amdgcn_mfma_f32_16x16x32_f16(A0[1], b1, C0g[j], 0, 0, 0);
            C1g[j] = __builtin_amdgcn_mfma_f32_16x16x32_f16(A1[1], b1, C1g[j], 0, 0, 0);
            C0g[j] = __builtin_amdgcn_mfma_f32_16x16x32_f16(A0[2], b2, C0g[j], 0, 0, 0);
            C1g[j] = __builtin_amdgcn_mfma_f32_16x16x32_f16(A1[2], b2, C1g[j], 0, 0, 0);
        }
        // fused epilogue (R5-verified): desc = num/(den+eps) -> s_d[i][k][bb]
        #pragma unroll
        for (int j = 0; j < 4; ++j) {
            const int nt = g * 4 + j;
            float den[5], inv[5];
            #pragma unroll
            for (int r = 0; r < 4; ++r) den[r] = __shfl(C1g[j][r], 16 + t);
            den[4] = __shfl(C1g[j][0], 32 + t);
            #pragma unroll
            for (int r = 0; r < NRH; ++r) {
                const float x = den[r] + EPSF;
                float vv = __builtin_amdgcn_rcpf(x);
                inv[r] = vv * (2.0f - x * vv);
            }
            #pragma unroll
            for (int reg = 0; reg < 4; ++reg)
                s_d[kq * 1280 + nt * DSTR + reg * 16 + t] =
                    (_Float16)(C0g[j][reg] * inv[reg]);
            if (kq == 0) {
                #pragma unroll
                for (int reg = 0; reg < 4; ++reg)
                    s_d[reg * 1280 + nt * DSTR + 64 + t] =
                        (_Float16)(C1g[j][reg] * inv[4]);
            }
        }
    }

    // ---- phase 2 (R4/R5-verified): per i, conv = desc @ W_i, max over k ----
    #pragma unroll
    for (int i = 0; i < 4; ++i) {
        f32x4 Cc[5];
        #pragma unroll
        for (int tile = 0; tile < 5; ++tile) Cc[tile] = (f32x4){0.f, 0.f, 0.f, 0.f};
        #pragma unroll
        for (int ks = 0; ks < 3; ++ks) {
            const half8 a = *(const half8*)(s_d + i * 1280 + t * DSTR + ks * 32 + kq * 8);
            #pragma unroll
            for (int tile = 0; tile < 5; ++tile) {
                half8 b;
                if (useWs) {
                    b = wsv[(size_t)((NSET_C + (i * 5 + tile) * 3 + ks) * 64 + lane)];
                } else {
                    const int cc  = tile * 16 + t;
                    const int bb0 = ks * 32 + kq * 8;
                    #pragma unroll
                    for (int j = 0; j < 8; ++j) {
                        const int bb = bb0 + j;
                        b[j] = (_Float16)((bb < NBINS) ? Wc[i * NBINS * NBINS + bb * NBINS + cc] : 0.0f);
                    }
                }
                Cc[tile] = __builtin_amdgcn_mfma_f32_16x16x32_f16(a, b, Cc[tile], 0, 0, 0);
            }
        }
        #pragma unroll
        for (int tile = 0; tile < 5; ++tile) {
            float m = fmaxf(fmaxf(Cc[tile][0], Cc[tile][1]), fmaxf(Cc[tile][2], Cc[tile][3]));
            m = fmaxf(m, __shfl_xor(m, 16));
            m = fmaxf(m, __shfl_xor(m, 32));
            if (lane < 16) {
                const int cc = tile * 16 + lane;
                out[(size_t)n * 320 + i * NBINS + cc] =
                    fmaxf(m + bcv[i * NBINS + cc], 0.0f);
            }
        }
    }
}

extern "C" void kernel_launch(void* const* d_in, const int* in_sizes, int n_in,
                              void* d_out, int out_size, void* d_ws, size_t ws_size,
                              hipStream_t stream) {
    const float* rho   = (const float*)d_in[0];
    const float* theta = (const float*)d_in[1];
    const float* feat  = (const float*)d_in[2];
    const float* mask  = (const float*)d_in[3];
    const float* mu_r  = (const float*)d_in[4];
    const float* sg_r  = (const float*)d_in[5];
    const float* mu_t  = (const float*)d_in[6];
    const float* sg_t  = (const float*)d_in[7];
    const float* W     = (const float*)d_in[8];
    const float* bconv = (const float*)d_in[9];
    float* outp = (float*)d_out;

    const int nsamp = in_sizes[0] / NVERT;
    const int useWs = (ws_size >= (size_t)WS_BYTES) ? 1 : 0;
    _Float16* wsh = (_Float16*)d_ws;

    if (useWs) prep_frags<<<NSET_C + NSET_W, 64, 0, stream>>>(W, sg_t, wsh);

    masif_geo_conv<<<nsamp, 64, 0, stream>>>(
        rho, theta, feat, mask, mu_r, sg_r, mu_t, sg_t, W, bconv,
        wsh, useWs, nsamp, outp);
}

// Round 16
// 131.645 us; speedup vs baseline: 1.1183x; 1.0711x over previous
//
#include <hip/hip_runtime.h>
#include <math.h>

#define NBINS 80
#define NVERT 128
#define NRH 5
#define NDEG 6           // Taylor terms d=0..5; remainder ~1e-5 (<< f16 eps)

#define PSTR 136         // halves per P/M row; cols 0..127 data, 128..135 pad
#define VSTR 32          // halves per VT row
#define DSTR 80          // halves per desc row

#define OFF_VT 6800      // P/M: 25*136*2 = 6800 B at [0,6800)
#define OFF_GM 12944     // VT: 96*32*2 = 6144 B at [6800,12944)
#define SLICE  13200     // gm: 256 B; desc overlays [0,10240) after chain1

#define NSET_C 48        // C-matrix frag sets: 16 nt x 3 ks
#define NSET_W 60        // W frag sets: 4 i x 5 tiles x 3 ks
#define WS_BYTES ((NSET_C + NSET_W) * 64 * 8 * 2)

typedef _Float16 half8 __attribute__((ext_vector_type(8)));
typedef float f32x4 __attribute__((ext_vector_type(4)));

// ---- prep: constant C-matrix frags + W frags in d_ws ----
// C[(a,d)][(nt,t)] = exp2(Kt*s^2) * z^d/d!,  s=(((a+nt)&15)-t)*DLT + DLT/2,
// z = 2*ln2*Kt*s*(DLT/2); pairs with V[c][(a,d)] = gam_c * u_c^d.
__global__ __launch_bounds__(64) void prep_frags(const float* __restrict__ Wc,
                                                 const float* __restrict__ sig_th,
                                                 _Float16* __restrict__ ws) {
    const int blk  = blockIdx.x;
    const int lane = threadIdx.x;
    constexpr float TWO_PI = 6.28318530717958647692f;
    constexpr float DLT    = TWO_PI / 16.0f;
    constexpr float LN2    = 0.69314718055994530942f;
    half8 h;
    if (blk < NSET_C) {
        constexpr float LOG2E = 1.44269504088896340736f;
        constexpr float EPSF  = 1e-5f;
        const float st = sig_th[0];
        const float Kt = -LOG2E / (st * st + EPSF);
        const int ks = blk % 3;
        const int nt = blk / 3;
        const int t  = lane & 15;
        const int q  = lane >> 4;
        #pragma unroll
        for (int j = 0; j < 8; ++j) {
            const int k = ks * 32 + q * 8 + j;     // 0..95
            const int a = k / NDEG;
            const int d = k % NDEG;
            const int m = ((a + nt) & 15) - t;
            const float s = fmaf((float)m, DLT, 0.5f * DLT);
            const float z = 2.0f * LN2 * Kt * s * (0.5f * DLT);
            float val = exp2f(Kt * s * s);
            for (int dd = 1; dd <= d; ++dd) val *= z / (float)dd;
            h[j] = (_Float16)val;
        }
    } else {
        const int e    = blk - NSET_C;
        const int ks   = e % 3;
        const int tile = (e / 3) % 5;
        const int i    = e / 15;
        const int cc   = tile * 16 + (lane & 15);
        const int bb0  = ks * 32 + (lane >> 4) * 8;
        #pragma unroll
        for (int j = 0; j < 8; ++j) {
            const int bb = bb0 + j;
            h[j] = (_Float16)((bb < NBINS) ? Wc[i * NBINS * NBINS + bb * NBINS + cc] : 0.0f);
        }
    }
    *(half8*)(ws + ((size_t)blk * 64 + lane) * 8) = h;
}

// R10-verified data structures. R15 theory: the fully-unrolled body (~40 KB
// code) thrashes the 32 KB L1 I-cache -> ~95% no-issue stall. Fix: roll the
// chain2 g-loop and phase2 i-loop (unroll 1; inner reg-array loops stay
// unrolled), and template out the non-ws fallback so its huge exp2-Taylor
// code lives in a separate (never-hot) kernel body.
template <int USEWS>
__global__ __launch_bounds__(64) void masif_geo_conv(
    const float* __restrict__ rho_c,
    const float* __restrict__ th_c,
    const float* __restrict__ feat_g,
    const float* __restrict__ mask_g,
    const float* __restrict__ mu_rho,
    const float* __restrict__ sig_rho,
    const float* __restrict__ mu_th,
    const float* __restrict__ sig_th,
    const float* __restrict__ Wc,
    const float* __restrict__ bcv,
    const _Float16* __restrict__ ws,
    const int nsamp,
    float* __restrict__ out)
{
    const int lane = threadIdx.x;
    const int n    = blockIdx.x;
    if (n >= nsamp) return;

    const int t  = lane & 15;
    const int kq = lane >> 4;

    __shared__ __align__(16) char s_raw[SLICE];
    _Float16* s_PM = (_Float16*)(s_raw);            // P (A) / M (B) / desc overlay
    _Float16* s_vt = (_Float16*)(s_raw + OFF_VT);
    _Float16* s_gm = (_Float16*)(s_raw + OFF_GM);
    _Float16* s_d  = (_Float16*)(s_raw);

    constexpr float LOG2E   = 1.44269504088896340736f;
    constexpr float TWO_PI  = 6.28318530717958647692f;
    constexpr float DLT     = TWO_PI / 16.0f;
    constexpr float INV_DLT = 16.0f / TWO_PI;
    constexpr float EPSF    = 1e-5f;

    const float st = sig_th[0];
    const float Kt = -LOG2E / (st * st + EPSF);
    const float sr = sig_rho[0];
    const float Kr = -LOG2E / (sr * sr + EPSF);
    float mr[NRH];
    #pragma unroll
    for (int r = 0; r < NRH; ++r) mr[r] = mu_rho[r * 16];

    // ---- zero P incl. pads (25*136 halves = 425 int4) ----
    #pragma unroll
    for (int x = 0; x < 7; ++x) {
        const int idx = x * 64 + lane;
        if (idx < 425) ((int4*)s_PM)[idx] = make_int4(0, 0, 0, 0);
    }

    // ---- compaction (R10 layout; loads hoisted) ----
    float  mv[2], thv[2], rhov[2];
    float4 fvv[2];
    #pragma unroll
    for (int rr = 0; rr < 2; ++rr) {
        const int v = rr * 64 + lane;
        mv[rr]   = mask_g[n * NVERT + v];
        thv[rr]  = th_c[n * NVERT + v];
        rhov[rr] = rho_c[n * NVERT + v];
        fvv[rr]  = *(const float4*)&feat_g[(n * NVERT + v) * 4];
    }
    int cbase = 0;
    #pragma unroll
    for (int rr = 0; rr < 2; ++rr) {
        const float m = mv[rr];
        const bool act = (m != 0.0f);
        const unsigned long long bal = __ballot(act);
        if (act) {
            const int pos = cbase + (int)__popcll(bal & ((1ull << lane) - 1ull));
            const float th0 = thv[rr];
            const float rho = rhov[rr];
            int aa = (int)floorf(th0 * INV_DLT);
            aa = aa > 15 ? 15 : (aa < 0 ? 0 : aa);
            const float rvp = th0 - (float)aa * DLT - 0.5f * DLT;   // [-DLT/2, DLT/2)
            float R[NRH];
            #pragma unroll
            for (int r = 0; r < NRH; ++r) {
                const float dr = rho - mr[r];
                R[r] = m * exp2f(Kr * dr * dr);
            }
            const float fv[4] = {fvv[rr].x, fvv[rr].y, fvv[rr].z, fvv[rr].w};
            #pragma unroll
            for (int f = 0; f < 4; ++f) {
                #pragma unroll
                for (int r = 0; r < 4; ++r)
                    s_PM[(f * 4 + r) * PSTR + pos] = (_Float16)(fv[f] * R[r]);
                s_PM[(16 + f) * PSTR + pos] = (_Float16)(fv[f] * R[4]);
            }
            #pragma unroll
            for (int r = 0; r < NRH; ++r)
                s_PM[(20 + r) * PSTR + pos] = (_Float16)R[r];
            s_PM[(pos >> 3) * PSTR + 128 + (pos & 7)] = (_Float16)(rvp * (2.0f * INV_DLT));
            ((char*)s_PM)[(16 + (pos >> 4)) * 2 * PSTR + 256 + (pos & 15)] = (char)aa;
            s_gm[pos] = (_Float16)exp2f(Kt * rvp * rvp);
        }
        cbase += (int)__popcll(bal);
    }
    const int nc = cbase;   // wave-uniform

    // ---- chain 1: M[25x96] = P[25x128c] @ V[128c x 96(a,d)], chunks of 32 ----
    f32x4 M0[NDEG], M1[NDEG];
    #pragma unroll
    for (int ct = 0; ct < NDEG; ++ct) {
        M0[ct] = (f32x4){0.f, 0.f, 0.f, 0.f};
        M1[ct] = (f32x4){0.f, 0.f, 0.f, 0.f};
    }
    const int nch = (nc + 31) >> 5;
    #pragma unroll 1
    for (int ch = 0; ch < nch; ++ch) {
        #pragma unroll
        for (int x = 0; x < 6; ++x)
            ((int4*)s_vt)[x * 64 + lane] = make_int4(0, 0, 0, 0);
        {
            const int cl = lane >> 1;
            const int cg = ch * 32 + cl;
            if (cg < nc) {
                const float u = (float)s_PM[(cg >> 3) * PSTR + 128 + (cg & 7)];
                const float g = (float)s_gm[cg];
                const int   a = (int)((char*)s_PM)[(16 + (cg >> 4)) * 2 * PSTR + 256 + (cg & 15)];
                const int  dh = (lane & 1) * 3;
                float p0, p1, p2;
                if (dh == 0) { p0 = 1.0f; p1 = u; p2 = u * u; }
                else { const float u2 = u * u; p0 = u2 * u; p1 = u2 * u2; p2 = p0 * u2; }
                const int bi = (a * NDEG + dh) * VSTR + cl;
                s_vt[bi]            = (_Float16)(g * p0);
                s_vt[bi + VSTR]     = (_Float16)(g * p1);
                s_vt[bi + 2 * VSTR] = (_Float16)(g * p2);
            }
        }
        // A-frags; t>8 on tile1 reads rows 25..31 (benign -> unread M1 rows)
        const half8 a0 = *(const half8*)(s_PM + t * PSTR + ch * 32 + kq * 8);
        const half8 a1 = *(const half8*)(s_PM + (16 + t) * PSTR + ch * 32 + kq * 8);
        #pragma unroll
        for (int ct = 0; ct < NDEG; ++ct) {
            const half8 b = *(const half8*)(s_vt + (ct * 16 + t) * VSTR + kq * 8);
            M0[ct] = __builtin_amdgcn_mfma_f32_16x16x32_f16(a0, b, M0[ct], 0, 0, 0);
            M1[ct] = __builtin_amdgcn_mfma_f32_16x16x32_f16(a1, b, M1[ct], 0, 0, 0);
        }
    }

    // ---- M -> LDS f16 A-layout (overlays P). D: col=t, row=kq*4+reg ----
    #pragma unroll
    for (int ct = 0; ct < NDEG; ++ct) {
        const int md = ct * 16 + t;
        #pragma unroll
        for (int reg = 0; reg < 4; ++reg) {
            s_PM[(kq * 4 + reg) * PSTR + md] = (_Float16)M0[ct][reg];
            if (kq * 4 + reg < 9)
                s_PM[(16 + kq * 4 + reg) * PSTR + md] = (_Float16)M1[ct][reg];
        }
    }

    // ---- chain2 A-frags -> regs (24 VGPRs); M LDS region dies here ----
    half8 A0[3], A1[3];
    #pragma unroll
    for (int ks = 0; ks < 3; ++ks) {
        A0[ks] = *(const half8*)(s_PM + t * PSTR + ks * 32 + kq * 8);
        A1[ks] = *(const half8*)(s_PM + (16 + t) * PSTR + ks * 32 + kq * 8);
    }

    // ---- chain 2: g-loop ROLLED (code size); j-loop unrolled (reg arrays) ----
    const half8* wsv = (const half8*)ws;
    #pragma unroll 1
    for (int g = 0; g < 4; ++g) {
        f32x4 C0g[4], C1g[4];
        #pragma unroll
        for (int j = 0; j < 4; ++j) {
            C0g[j] = (f32x4){0.f, 0.f, 0.f, 0.f};
            C1g[j] = (f32x4){0.f, 0.f, 0.f, 0.f};
        }
        #pragma unroll
        for (int j = 0; j < 4; ++j) {
            const int nt = g * 4 + j;
            half8 b0, b1, b2;
            if (USEWS) {
                b0 = wsv[(size_t)((nt * 3 + 0) * 64 + lane)];
                b1 = wsv[(size_t)((nt * 3 + 1) * 64 + lane)];
                b2 = wsv[(size_t)((nt * 3 + 2) * 64 + lane)];
            } else {
                #pragma unroll
                for (int ks = 0; ks < 3; ++ks) {
                    half8 bb;
                    #pragma unroll
                    for (int jj = 0; jj < 8; ++jj) {
                        const int k = ks * 32 + kq * 8 + jj;
                        const int a = k / NDEG, d = k % NDEG;
                        const int mm = ((a + nt) & 15) - t;
                        const float s = fmaf((float)mm, DLT, 0.5f * DLT);
                        const float z = 2.0f * 0.69314718055994530942f * Kt * s * (0.5f * DLT);
                        float val = exp2f(Kt * s * s);
                        for (int dd = 1; dd <= d; ++dd) val *= z / (float)dd;
                        bb[jj] = (_Float16)val;
                    }
                    if (ks == 0) b0 = bb; else if (ks == 1) b1 = bb; else b2 = bb;
                }
            }
            C0g[j] = __builtin_amdgcn_mfma_f32_16x16x32_f16(A0[0], b0, C0g[j], 0, 0, 0);
            C1g[j] = __builtin_amdgcn_mfma_f32_16x16x32_f16(A1[0], b0, C1g[j], 0, 0, 0);
            C0g[j] = __builtin_amdgcn_mfma_f32_16x16x32_f16(A0[1], b1, C0g[j], 0, 0, 0);
            C1g[j] = __builtin_amdgcn_mfma_f32_16x16x32_f16(A1[1], b1, C1g[j], 0, 0, 0);
            C0g[j] = __builtin_amdgcn_mfma_f32_16x16x32_f16(A0[2], b2, C0g[j], 0, 0, 0);
            C1g[j] = __builtin_amdgcn_mfma_f32_16x16x32_f16(A1[2], b2, C1g[j], 0, 0, 0);
        }
        // fused epilogue (R5-verified): desc = num/(den+eps) -> s_d[i][k][bb]
        #pragma unroll
        for (int j = 0; j < 4; ++j) {
            const int nt = g * 4 + j;
            float den[5], inv[5];
            #pragma unroll
            for (int r = 0; r < 4; ++r) den[r] = __shfl(C1g[j][r], 16 + t);
            den[4] = __shfl(C1g[j][0], 32 + t);
            #pragma unroll
            for (int r = 0; r < NRH; ++r) {
                const float x = den[r] + EPSF;
                float vv = __builtin_amdgcn_rcpf(x);
                inv[r] = vv * (2.0f - x * vv);
            }
            #pragma unroll
            for (int reg = 0; reg < 4; ++reg)
                s_d[kq * 1280 + nt * DSTR + reg * 16 + t] =
                    (_Float16)(C0g[j][reg] * inv[reg]);
            if (kq == 0) {
                #pragma unroll
                for (int reg = 0; reg < 4; ++reg)
                    s_d[reg * 1280 + nt * DSTR + 64 + t] =
                        (_Float16)(C1g[j][reg] * inv[4]);
            }
        }
    }

    // ---- phase 2: i-loop ROLLED (code size); tile-loop unrolled ----
    #pragma unroll 1
    for (int i = 0; i < 4; ++i) {
        f32x4 Cc[5];
        #pragma unroll
        for (int tile = 0; tile < 5; ++tile) Cc[tile] = (f32x4){0.f, 0.f, 0.f, 0.f};
        #pragma unroll
        for (int ks = 0; ks < 3; ++ks) {
            const half8 a = *(const half8*)(s_d + i * 1280 + t * DSTR + ks * 32 + kq * 8);
            #pragma unroll
            for (int tile = 0; tile < 5; ++tile) {
                half8 b;
                if (USEWS) {
                    b = wsv[(size_t)((NSET_C + (i * 5 + tile) * 3 + ks) * 64 + lane)];
                } else {
                    const int cc  = tile * 16 + t;
                    const int bb0 = ks * 32 + kq * 8;
                    #pragma unroll
                    for (int j = 0; j < 8; ++j) {
                        const int bb = bb0 + j;
                        b[j] = (_Float16)((bb < NBINS) ? Wc[i * NBINS * NBINS + bb * NBINS + cc] : 0.0f);
                    }
                }
                Cc[tile] = __builtin_amdgcn_mfma_f32_16x16x32_f16(a, b, Cc[tile], 0, 0, 0);
            }
        }
        #pragma unroll
        for (int tile = 0; tile < 5; ++tile) {
            float m = fmaxf(fmaxf(Cc[tile][0], Cc[tile][1]), fmaxf(Cc[tile][2], Cc[tile][3]));
            m = fmaxf(m, __shfl_xor(m, 16));
            m = fmaxf(m, __shfl_xor(m, 32));
            if (lane < 16) {
                const int cc = tile * 16 + lane;
                out[(size_t)n * 320 + i * NBINS + cc] =
                    fmaxf(m + bcv[i * NBINS + cc], 0.0f);
            }
        }
    }
}

extern "C" void kernel_launch(void* const* d_in, const int* in_sizes, int n_in,
                              void* d_out, int out_size, void* d_ws, size_t ws_size,
                              hipStream_t stream) {
    const float* rho   = (const float*)d_in[0];
    const float* theta = (const float*)d_in[1];
    const float* feat  = (const float*)d_in[2];
    const float* mask  = (const float*)d_in[3];
    const float* mu_r  = (const float*)d_in[4];
    const float* sg_r  = (const float*)d_in[5];
    const float* mu_t  = (const float*)d_in[6];
    const float* sg_t  = (const float*)d_in[7];
    const float* W     = (const float*)d_in[8];
    const float* bconv = (const float*)d_in[9];
    float* outp = (float*)d_out;

    const int nsamp = in_sizes[0] / NVERT;
    const int useWs = (ws_size >= (size_t)WS_BYTES) ? 1 : 0;
    _Float16* wsh = (_Float16*)d_ws;

    if (useWs) {
        prep_frags<<<NSET_C + NSET_W, 64, 0, stream>>>(W, sg_t, wsh);
        masif_geo_conv<1><<<nsamp, 64, 0, stream>>>(
            rho, theta, feat, mask, mu_r, sg_r, mu_t, sg_t, W, bconv,
            wsh, nsamp, outp);
    } else {
        masif_geo_conv<0><<<nsamp, 64, 0, stream>>>(
            rho, theta, feat, mask, mu_r, sg_r, mu_t, sg_t, W, bconv,
            wsh, nsamp, outp);
    }
}

// Round 17
// 124.583 us; speedup vs baseline: 1.1817x; 1.0567x over previous
//
#include <hip/hip_runtime.h>
#include <math.h>

#define NBINS 80
#define NVERT 128
#define NRH 5
#define NDEG 6           // Taylor terms d=0..5; remainder ~1e-5 (<< f16 eps)

#define PSTR 136         // halves per P/M row; cols 0..127 data, 128..135 pad
#define VSTR 32          // halves per VT row
#define DSTR 80          // halves per desc row

#define OFF_VT 6800      // P/M: 25*136*2 = 6800 B at [0,6800)
#define VTSZ   6144      // per-wave VT copy: 96*32*2
#define OFF_GM 19088     // gm f16 x 128 = 256 B
#define OFF_CNT 19344    // 2 ints
#define SLICE  19360     // desc overlays [0,10240) after chain1 (VT dead)

#define NSET_C 48        // C-matrix frag sets: 16 nt x 3 ks
#define NSET_W 60        // W frag sets: 4 i x 5 tiles x 3 ks
#define WS_BYTES ((NSET_C + NSET_W) * 64 * 8 * 2)

typedef _Float16 half8 __attribute__((ext_vector_type(8)));
typedef float f32x4 __attribute__((ext_vector_type(4)));

// ---- prep: constant C-matrix frags + W frags in d_ws (unchanged, verified) ----
__global__ __launch_bounds__(64) void prep_frags(const float* __restrict__ Wc,
                                                 const float* __restrict__ sig_th,
                                                 _Float16* __restrict__ ws) {
    const int blk  = blockIdx.x;
    const int lane = threadIdx.x;
    constexpr float TWO_PI = 6.28318530717958647692f;
    constexpr float DLT    = TWO_PI / 16.0f;
    constexpr float LN2    = 0.69314718055994530942f;
    half8 h;
    if (blk < NSET_C) {
        constexpr float LOG2E = 1.44269504088896340736f;
        constexpr float EPSF  = 1e-5f;
        const float st = sig_th[0];
        const float Kt = -LOG2E / (st * st + EPSF);
        const int ks = blk % 3;
        const int nt = blk / 3;
        const int t  = lane & 15;
        const int q  = lane >> 4;
        #pragma unroll
        for (int j = 0; j < 8; ++j) {
            const int k = ks * 32 + q * 8 + j;     // 0..95
            const int a = k / NDEG;
            const int d = k % NDEG;
            const int m = ((a + nt) & 15) - t;
            const float s = fmaf((float)m, DLT, 0.5f * DLT);
            const float z = 2.0f * LN2 * Kt * s * (0.5f * DLT);
            float val = exp2f(Kt * s * s);
            for (int dd = 1; dd <= d; ++dd) val *= z / (float)dd;
            h[j] = (_Float16)val;
        }
    } else {
        const int e    = blk - NSET_C;
        const int ks   = e % 3;
        const int tile = (e / 3) % 5;
        const int i    = e / 15;
        const int cc   = tile * 16 + (lane & 15);
        const int bb0  = ks * 32 + (lane >> 4) * 8;
        #pragma unroll
        for (int j = 0; j < 8; ++j) {
            const int bb = bb0 + j;
            h[j] = (_Float16)((bb < NBINS) ? Wc[i * NBINS * NBINS + bb * NBINS + cc] : 0.0f);
        }
    }
    *(half8*)(ws + ((size_t)blk * 64 + lane) * 8) = h;
}

// Cooperative 2-wave block, one sample. Residency is block-capped (~8/CU,
// observed R8-R15 invariant to LDS size), so: halve per-wave work + 2 waves
// per block slot. Work split: compaction by vertex half; chain1 by M tile
// (each wave has its OWN VT copy -> no per-chunk barriers); chain2 by
// nt-group pairs; phase2 by feature pairs. 4 barriers total.
template <int USEWS>
__global__ __launch_bounds__(128) void masif_geo_conv(
    const float* __restrict__ rho_c,
    const float* __restrict__ th_c,
    const float* __restrict__ feat_g,
    const float* __restrict__ mask_g,
    const float* __restrict__ mu_rho,
    const float* __restrict__ sig_rho,
    const float* __restrict__ mu_th,
    const float* __restrict__ sig_th,
    const float* __restrict__ Wc,
    const float* __restrict__ bcv,
    const _Float16* __restrict__ ws,
    const int nsamp,
    float* __restrict__ out)
{
    const int tid  = threadIdx.x;
    const int wave = tid >> 6;
    const int lane = tid & 63;
    const int n    = blockIdx.x;          // grid == nsamp exactly (no early return: barriers)

    const int t  = lane & 15;
    const int kq = lane >> 4;

    __shared__ __align__(16) char s_raw[SLICE];
    _Float16* s_PM = (_Float16*)(s_raw);                    // P / M / desc overlay
    _Float16* s_vtw = (_Float16*)(s_raw + OFF_VT + wave * VTSZ);  // own VT copy
    _Float16* s_gm = (_Float16*)(s_raw + OFF_GM);
    int*      s_cnt = (int*)(s_raw + OFF_CNT);
    _Float16* s_d  = (_Float16*)(s_raw);

    constexpr float LOG2E   = 1.44269504088896340736f;
    constexpr float TWO_PI  = 6.28318530717958647692f;
    constexpr float DLT     = TWO_PI / 16.0f;
    constexpr float INV_DLT = 16.0f / TWO_PI;
    constexpr float EPSF    = 1e-5f;

    const float st = sig_th[0];
    const float Kt = -LOG2E / (st * st + EPSF);
    const float sr = sig_rho[0];
    const float Kr = -LOG2E / (sr * sr + EPSF);
    float mr[NRH];
    #pragma unroll
    for (int r = 0; r < NRH; ++r) mr[r] = mu_rho[r * 16];

    // ---- zero P incl. pads (425 int4, 128 threads) ----
    #pragma unroll
    for (int x = 0; x < 4; ++x) {
        const int idx = x * 128 + tid;
        if (idx < 425) ((int4*)s_PM)[idx] = make_int4(0, 0, 0, 0);
    }

    // ---- compaction: wave w handles verts 64w..64w+63 ----
    const int v = wave * 64 + lane;
    const float  m   = mask_g[n * NVERT + v];
    const float  th0 = th_c[n * NVERT + v];
    const float  rho = rho_c[n * NVERT + v];
    const float4 f4  = *(const float4*)&feat_g[(n * NVERT + v) * 4];
    const bool act = (m != 0.0f);
    const unsigned long long bal = __ballot(act);
    if (lane == 0) s_cnt[wave] = (int)__popcll(bal);
    __syncthreads();                                        // [1] counts + P zero
    const int base = wave ? s_cnt[0] : 0;
    const int nc   = s_cnt[0] + s_cnt[1];
    if (act) {
        const int pos = base + (int)__popcll(bal & ((1ull << lane) - 1ull));
        int aa = (int)floorf(th0 * INV_DLT);
        aa = aa > 15 ? 15 : (aa < 0 ? 0 : aa);
        const float rvp = th0 - (float)aa * DLT - 0.5f * DLT;   // [-DLT/2, DLT/2)
        float R[NRH];
        #pragma unroll
        for (int r = 0; r < NRH; ++r) {
            const float dr = rho - mr[r];
            R[r] = m * exp2f(Kr * dr * dr);
        }
        const float fv[4] = {f4.x, f4.y, f4.z, f4.w};
        #pragma unroll
        for (int f = 0; f < 4; ++f) {
            #pragma unroll
            for (int r = 0; r < 4; ++r)
                s_PM[(f * 4 + r) * PSTR + pos] = (_Float16)(fv[f] * R[r]);
            s_PM[(16 + f) * PSTR + pos] = (_Float16)(fv[f] * R[4]);
        }
        #pragma unroll
        for (int r = 0; r < NRH; ++r)
            s_PM[(20 + r) * PSTR + pos] = (_Float16)R[r];
        s_PM[(pos >> 3) * PSTR + 128 + (pos & 7)] = (_Float16)(rvp * (2.0f * INV_DLT));
        ((char*)s_PM)[(16 + (pos >> 4)) * 2 * PSTR + 256 + (pos & 15)] = (char)aa;
        s_gm[pos] = (_Float16)exp2f(Kt * rvp * rvp);
    }
    __syncthreads();                                        // [2] P/gm/tails complete

    // ---- chain 1: wave0 -> M tile0 (rows 0-15), wave1 -> tile1 (rows 16-24) ----
    // Each wave: own VT copy, 6 MFMAs/chunk. Wave1 A-reads rows 25-31 are
    // in-slice garbage -> discarded M rows 9-15 (per-row MFMA independence).
    f32x4 M[NDEG];
    #pragma unroll
    for (int ct = 0; ct < NDEG; ++ct) M[ct] = (f32x4){0.f, 0.f, 0.f, 0.f};
    const int arow = wave ? (16 + t) : t;
    const int nch = (nc + 31) >> 5;
    #pragma unroll 1
    for (int ch = 0; ch < nch; ++ch) {
        #pragma unroll
        for (int x = 0; x < 6; ++x)
            ((int4*)s_vtw)[x * 64 + lane] = make_int4(0, 0, 0, 0);
        {
            const int cl = lane >> 1;
            const int cg = ch * 32 + cl;
            if (cg < nc) {
                const float u = (float)s_PM[(cg >> 3) * PSTR + 128 + (cg & 7)];
                const float g = (float)s_gm[cg];
                const int   a = (int)((char*)s_PM)[(16 + (cg >> 4)) * 2 * PSTR + 256 + (cg & 15)];
                const int  dh = (lane & 1) * 3;
                float p0, p1, p2;
                if (dh == 0) { p0 = 1.0f; p1 = u; p2 = u * u; }
                else { const float u2 = u * u; p0 = u2 * u; p1 = u2 * u2; p2 = p0 * u2; }
                const int bi = (a * NDEG + dh) * VSTR + cl;
                s_vtw[bi]            = (_Float16)(g * p0);
                s_vtw[bi + VSTR]     = (_Float16)(g * p1);
                s_vtw[bi + 2 * VSTR] = (_Float16)(g * p2);
            }
        }
        const half8 a = *(const half8*)(s_PM + arow * PSTR + ch * 32 + kq * 8);
        #pragma unroll
        for (int ct = 0; ct < NDEG; ++ct) {
            const half8 b = *(const half8*)(s_vtw + (ct * 16 + t) * VSTR + kq * 8);
            M[ct] = __builtin_amdgcn_mfma_f32_16x16x32_f16(a, b, M[ct], 0, 0, 0);
        }
    }

    // ---- M -> LDS f16 A-layout. D: col=t, row=kq*4+reg ----
    #pragma unroll
    for (int ct = 0; ct < NDEG; ++ct) {
        const int md = ct * 16 + t;
        #pragma unroll
        for (int reg = 0; reg < 4; ++reg) {
            const int lr = kq * 4 + reg;
            if (wave == 0)
                s_PM[lr * PSTR + md] = (_Float16)M[ct][reg];
            else if (lr < 9)
                s_PM[(16 + lr) * PSTR + md] = (_Float16)M[ct][reg];
        }
    }
    __syncthreads();                                        // [3] M complete

    // ---- chain2 A-frags -> regs (both tiles, both waves) ----
    half8 A0[3], A1[3];
    #pragma unroll
    for (int ks = 0; ks < 3; ++ks) {
        A0[ks] = *(const half8*)(s_PM + t * PSTR + ks * 32 + kq * 8);
        A1[ks] = *(const half8*)(s_PM + (16 + t) * PSTR + ks * 32 + kq * 8);
    }

    // ---- chain 2: wave w -> nt-groups 2w, 2w+1; fused epilogue ----
    const half8* wsv = (const half8*)ws;
    #pragma unroll 1
    for (int gg = 0; gg < 2; ++gg) {
        const int g = wave * 2 + gg;
        f32x4 C0g[4], C1g[4];
        #pragma unroll
        for (int j = 0; j < 4; ++j) {
            C0g[j] = (f32x4){0.f, 0.f, 0.f, 0.f};
            C1g[j] = (f32x4){0.f, 0.f, 0.f, 0.f};
        }
        #pragma unroll
        for (int j = 0; j < 4; ++j) {
            const int nt = g * 4 + j;
            half8 b0, b1, b2;
            if (USEWS) {
                b0 = wsv[(size_t)((nt * 3 + 0) * 64 + lane)];
                b1 = wsv[(size_t)((nt * 3 + 1) * 64 + lane)];
                b2 = wsv[(size_t)((nt * 3 + 2) * 64 + lane)];
            } else {
                #pragma unroll
                for (int ks = 0; ks < 3; ++ks) {
                    half8 bb;
                    #pragma unroll
                    for (int jj = 0; jj < 8; ++jj) {
                        const int k = ks * 32 + kq * 8 + jj;
                        const int a = k / NDEG, d = k % NDEG;
                        const int mm = ((a + nt) & 15) - t;
                        const float s = fmaf((float)mm, DLT, 0.5f * DLT);
                        const float z = 2.0f * 0.69314718055994530942f * Kt * s * (0.5f * DLT);
                        float val = exp2f(Kt * s * s);
                        for (int dd = 1; dd <= d; ++dd) val *= z / (float)dd;
                        bb[jj] = (_Float16)val;
                    }
                    if (ks == 0) b0 = bb; else if (ks == 1) b1 = bb; else b2 = bb;
                }
            }
            C0g[j] = __builtin_amdgcn_mfma_f32_16x16x32_f16(A0[0], b0, C0g[j], 0, 0, 0);
            C1g[j] = __builtin_amdgcn_mfma_f32_16x16x32_f16(A1[0], b0, C1g[j], 0, 0, 0);
            C0g[j] = __builtin_amdgcn_mfma_f32_16x16x32_f16(A0[1], b1, C0g[j], 0, 0, 0);
            C1g[j] = __builtin_amdgcn_mfma_f32_16x16x32_f16(A1[1], b1, C1g[j], 0, 0, 0);
            C0g[j] = __builtin_amdgcn_mfma_f32_16x16x32_f16(A0[2], b2, C0g[j], 0, 0, 0);
            C1g[j] = __builtin_amdgcn_mfma_f32_16x16x32_f16(A1[2], b2, C1g[j], 0, 0, 0);
        }
        // fused epilogue (R5-verified): desc = num/(den+eps) -> s_d[i][k][bb]
        #pragma unroll
        for (int j = 0; j < 4; ++j) {
            const int nt = g * 4 + j;
            float den[5], inv[5];
            #pragma unroll
            for (int r = 0; r < 4; ++r) den[r] = __shfl(C1g[j][r], 16 + t);
            den[4] = __shfl(C1g[j][0], 32 + t);
            #pragma unroll
            for (int r = 0; r < NRH; ++r) {
                const float x = den[r] + EPSF;
                float vv = __builtin_amdgcn_rcpf(x);
                inv[r] = vv * (2.0f - x * vv);
            }
            #pragma unroll
            for (int reg = 0; reg < 4; ++reg)
                s_d[kq * 1280 + nt * DSTR + reg * 16 + t] =
                    (_Float16)(C0g[j][reg] * inv[reg]);
            if (kq == 0) {
                #pragma unroll
                for (int reg = 0; reg < 4; ++reg)
                    s_d[reg * 1280 + nt * DSTR + 64 + t] =
                        (_Float16)(C1g[j][reg] * inv[4]);
            }
        }
    }
    __syncthreads();                                        // [4] desc complete

    // ---- phase 2: wave w -> i = 2w, 2w+1 ----
    #pragma unroll 1
    for (int ii = 0; ii < 2; ++ii) {
        const int i = wave * 2 + ii;
        f32x4 Cc[5];
        #pragma unroll
        for (int tile = 0; tile < 5; ++tile) Cc[tile] = (f32x4){0.f, 0.f, 0.f, 0.f};
        #pragma unroll
        for (int ks = 0; ks < 3; ++ks) {
            const half8 a = *(const half8*)(s_d + i * 1280 + t * DSTR + ks * 32 + kq * 8);
            #pragma unroll
            for (int tile = 0; tile < 5; ++tile) {
                half8 b;
                if (USEWS) {
                    b = wsv[(size_t)((NSET_C + (i * 5 + tile) * 3 + ks) * 64 + lane)];
                } else {
                    const int cc  = tile * 16 + t;
                    const int bb0 = ks * 32 + kq * 8;
                    #pragma unroll
                    for (int j = 0; j < 8; ++j) {
                        const int bb = bb0 + j;
                        b[j] = (_Float16)((bb < NBINS) ? Wc[i * NBINS * NBINS + bb * NBINS + cc] : 0.0f);
                    }
                }
                Cc[tile] = __builtin_amdgcn_mfma_f32_16x16x32_f16(a, b, Cc[tile], 0, 0, 0);
            }
        }
        #pragma unroll
        for (int tile = 0; tile < 5; ++tile) {
            float mx = fmaxf(fmaxf(Cc[tile][0], Cc[tile][1]), fmaxf(Cc[tile][2], Cc[tile][3]));
            mx = fmaxf(mx, __shfl_xor(mx, 16));
            mx = fmaxf(mx, __shfl_xor(mx, 32));
            if (lane < 16) {
                const int cc = tile * 16 + lane;
                out[(size_t)n * 320 + i * NBINS + cc] =
                    fmaxf(mx + bcv[i * NBINS + cc], 0.0f);
            }
        }
    }
}

extern "C" void kernel_launch(void* const* d_in, const int* in_sizes, int n_in,
                              void* d_out, int out_size, void* d_ws, size_t ws_size,
                              hipStream_t stream) {
    const float* rho   = (const float*)d_in[0];
    const float* theta = (const float*)d_in[1];
    const float* feat  = (const float*)d_in[2];
    const float* mask  = (const float*)d_in[3];
    const float* mu_r  = (const float*)d_in[4];
    const float* sg_r  = (const float*)d_in[5];
    const float* mu_t  = (const float*)d_in[6];
    const float* sg_t  = (const float*)d_in[7];
    const float* W     = (const float*)d_in[8];
    const float* bconv = (const float*)d_in[9];
    float* outp = (float*)d_out;

    const int nsamp = in_sizes[0] / NVERT;
    const int useWs = (ws_size >= (size_t)WS_BYTES) ? 1 : 0;
    _Float16* wsh = (_Float16*)d_ws;

    if (useWs) {
        prep_frags<<<NSET_C + NSET_W, 64, 0, stream>>>(W, sg_t, wsh);
        masif_geo_conv<1><<<nsamp, 128, 0, stream>>>(
            rho, theta, feat, mask, mu_r, sg_r, mu_t, sg_t, W, bconv,
            wsh, nsamp, outp);
    } else {
        masif_geo_conv<0><<<nsamp, 128, 0, stream>>>(
            rho, theta, feat, mask, mu_r, sg_r, mu_t, sg_t, W, bconv,
            wsh, nsamp, outp);
    }
}

// Round 18
// 118.446 us; speedup vs baseline: 1.2429x; 1.0518x over previous
//
#include <hip/hip_runtime.h>
#include <math.h>

#define NBINS 80
#define NVERT 128
#define NRH 5
#define NDEG 6           // Taylor terms d=0..5; remainder ~1e-5 (<< f16 eps)

#define PSTR 136         // halves per P/M row; cols 0..127 data, 128..135 pad
#define VSTR 32          // halves per VT row
#define DSTR 80          // halves per desc row

#define OFF_VT 6800      // P/M: 25*136*2 = 6800 B at [0,6800)
#define VTSZ   3072      // per-wave VT: 48 rows x 32 halves (one a-half)
#define OFF_GM 19088     // gm f16 x 128 = 256 B  (VT: 4*3072 = [6800,19088))
#define OFF_CNT 19344    // 2 ints
#define SLICE  19360     // desc overlays [0,10240) after chain1 (VT dead)

#define NSET_C 48        // C-matrix frag sets: 16 nt x 3 ks
#define NSET_W 60        // W frag sets: 4 i x 5 tiles x 3 ks
#define WS_BYTES ((NSET_C + NSET_W) * 64 * 8 * 2)

typedef _Float16 half8 __attribute__((ext_vector_type(8)));
typedef float f32x4 __attribute__((ext_vector_type(4)));

// ---- prep: constant C-matrix frags + W frags in d_ws (unchanged, verified) ----
__global__ __launch_bounds__(64) void prep_frags(const float* __restrict__ Wc,
                                                 const float* __restrict__ sig_th,
                                                 _Float16* __restrict__ ws) {
    const int blk  = blockIdx.x;
    const int lane = threadIdx.x;
    constexpr float TWO_PI = 6.28318530717958647692f;
    constexpr float DLT    = TWO_PI / 16.0f;
    constexpr float LN2    = 0.69314718055994530942f;
    half8 h;
    if (blk < NSET_C) {
        constexpr float LOG2E = 1.44269504088896340736f;
        constexpr float EPSF  = 1e-5f;
        const float st = sig_th[0];
        const float Kt = -LOG2E / (st * st + EPSF);
        const int ks = blk % 3;
        const int nt = blk / 3;
        const int t  = lane & 15;
        const int q  = lane >> 4;
        #pragma unroll
        for (int j = 0; j < 8; ++j) {
            const int k = ks * 32 + q * 8 + j;     // 0..95
            const int a = k / NDEG;
            const int d = k % NDEG;
            const int m = ((a + nt) & 15) - t;
            const float s = fmaf((float)m, DLT, 0.5f * DLT);
            const float z = 2.0f * LN2 * Kt * s * (0.5f * DLT);
            float val = exp2f(Kt * s * s);
            for (int dd = 1; dd <= d; ++dd) val *= z / (float)dd;
            h[j] = (_Float16)val;
        }
    } else {
        const int e    = blk - NSET_C;
        const int ks   = e % 3;
        const int tile = (e / 3) % 5;
        const int i    = e / 15;
        const int cc   = tile * 16 + (lane & 15);
        const int bb0  = ks * 32 + (lane >> 4) * 8;
        #pragma unroll
        for (int j = 0; j < 8; ++j) {
            const int bb = bb0 + j;
            h[j] = (_Float16)((bb < NBINS) ? Wc[i * NBINS * NBINS + bb * NBINS + cc] : 0.0f);
        }
    }
    *(half8*)(ws + ((size_t)blk * 64 + lane) * 8) = h;
}

// Cooperative 4-wave block, one sample. Work split (R16 lesson: more waves
// per block-slot wins): compaction waves 0/1; chain1 by (M-tile x col-half)
// quadrant with PRIVATE 3 KB VT per wave (only its a-half -> half build cost,
// 3 MFMAs/chunk, disjoint M write, NO reduction); chain2 one nt-group/wave;
// phase2 one feature/wave. 5 barriers. R9: no persistent loop.
template <int USEWS>
__global__ __launch_bounds__(256) void masif_geo_conv(
    const float* __restrict__ rho_c,
    const float* __restrict__ th_c,
    const float* __restrict__ feat_g,
    const float* __restrict__ mask_g,
    const float* __restrict__ mu_rho,
    const float* __restrict__ sig_rho,
    const float* __restrict__ mu_th,
    const float* __restrict__ sig_th,
    const float* __restrict__ Wc,
    const float* __restrict__ bcv,
    const _Float16* __restrict__ ws,
    const int nsamp,
    float* __restrict__ out)
{
    const int tid  = threadIdx.x;
    const int wave = tid >> 6;
    const int lane = tid & 63;
    const int n    = blockIdx.x;          // grid == nsamp (no early return: barriers)

    const int t  = lane & 15;
    const int kq = lane >> 4;

    __shared__ __align__(16) char s_raw[SLICE];
    _Float16* s_PM  = (_Float16*)(s_raw);                       // P / M / desc overlay
    _Float16* s_vtw = (_Float16*)(s_raw + OFF_VT + wave * VTSZ); // private VT
    _Float16* s_gm  = (_Float16*)(s_raw + OFF_GM);
    int*      s_cnt = (int*)(s_raw + OFF_CNT);
    _Float16* s_d   = (_Float16*)(s_raw);

    constexpr float LOG2E   = 1.44269504088896340736f;
    constexpr float TWO_PI  = 6.28318530717958647692f;
    constexpr float DLT     = TWO_PI / 16.0f;
    constexpr float INV_DLT = 16.0f / TWO_PI;
    constexpr float EPSF    = 1e-5f;

    const float st = sig_th[0];
    const float Kt = -LOG2E / (st * st + EPSF);
    const float sr = sig_rho[0];
    const float Kr = -LOG2E / (sr * sr + EPSF);
    float mr[NRH];
    #pragma unroll
    for (int r = 0; r < NRH; ++r) mr[r] = mu_rho[r * 16];

    // ---- zero P incl. pads (425 int4, 256 threads) ----
    #pragma unroll
    for (int x = 0; x < 2; ++x) {
        const int idx = x * 256 + tid;
        if (idx < 425) ((int4*)s_PM)[idx] = make_int4(0, 0, 0, 0);
    }

    // ---- compaction: waves 0/1 handle verts 64w..64w+63; waves 2/3 wait ----
    bool act = false;
    unsigned long long bal = 0;
    float mv = 0.f, thv = 0.f, rhov = 0.f;
    float4 f4 = make_float4(0.f, 0.f, 0.f, 0.f);
    if (wave < 2) {
        const int v = wave * 64 + lane;
        mv   = mask_g[n * NVERT + v];
        thv  = th_c[n * NVERT + v];
        rhov = rho_c[n * NVERT + v];
        f4   = *(const float4*)&feat_g[(n * NVERT + v) * 4];
        act  = (mv != 0.0f);
        bal  = __ballot(act);
        if (lane == 0) s_cnt[wave] = (int)__popcll(bal);
    }
    __syncthreads();                                        // [1] counts + P zero
    const int nc = s_cnt[0] + s_cnt[1];
    if (act) {
        const int base = wave ? s_cnt[0] : 0;
        const int pos = base + (int)__popcll(bal & ((1ull << lane) - 1ull));
        int aa = (int)floorf(thv * INV_DLT);
        aa = aa > 15 ? 15 : (aa < 0 ? 0 : aa);
        const float rvp = thv - (float)aa * DLT - 0.5f * DLT;   // [-DLT/2, DLT/2)
        float R[NRH];
        #pragma unroll
        for (int r = 0; r < NRH; ++r) {
            const float dr = rhov - mr[r];
            R[r] = mv * exp2f(Kr * dr * dr);
        }
        const float fv[4] = {f4.x, f4.y, f4.z, f4.w};
        #pragma unroll
        for (int f = 0; f < 4; ++f) {
            #pragma unroll
            for (int r = 0; r < 4; ++r)
                s_PM[(f * 4 + r) * PSTR + pos] = (_Float16)(fv[f] * R[r]);
            s_PM[(16 + f) * PSTR + pos] = (_Float16)(fv[f] * R[4]);
        }
        #pragma unroll
        for (int r = 0; r < NRH; ++r)
            s_PM[(20 + r) * PSTR + pos] = (_Float16)R[r];
        s_PM[(pos >> 3) * PSTR + 128 + (pos & 7)] = (_Float16)(rvp * (2.0f * INV_DLT));
        ((char*)s_PM)[(16 + (pos >> 4)) * 2 * PSTR + 256 + (pos & 15)] = (char)aa;
        s_gm[pos] = (_Float16)exp2f(Kt * rvp * rvp);
    }
    __syncthreads();                                        // [2] P/gm/tails complete

    // ---- chain 1: wave -> (tile = w&1, col-half chalf = w>>1). Private VT
    //      holds only a in [8*chalf, 8*chalf+8) (48 rows); 3 MFMAs/chunk.
    //      Disjoint M quadrant writeback -> no reduction, no chunk barriers. ----
    const int tile  = wave & 1;
    const int chalf = wave >> 1;
    f32x4 M[3];
    #pragma unroll
    for (int lct = 0; lct < 3; ++lct) M[lct] = (f32x4){0.f, 0.f, 0.f, 0.f};
    const int arow = tile ? (16 + t) : t;
    const int nch = (nc + 31) >> 5;
    #pragma unroll 1
    for (int ch = 0; ch < nch; ++ch) {
        #pragma unroll
        for (int x = 0; x < 3; ++x)
            ((int4*)s_vtw)[x * 64 + lane] = make_int4(0, 0, 0, 0);
        {
            const int cl = lane >> 1;
            const int cg = ch * 32 + cl;
            if (cg < nc) {
                const int a = (int)((char*)s_PM)[(16 + (cg >> 4)) * 2 * PSTR + 256 + (cg & 15)];
                if ((a >> 3) == chalf) {
                    const float u = (float)s_PM[(cg >> 3) * PSTR + 128 + (cg & 7)];
                    const float g = (float)s_gm[cg];
                    const int  dh = (lane & 1) * 3;
                    float p0, p1, p2;
                    if (dh == 0) { p0 = 1.0f; p1 = u; p2 = u * u; }
                    else { const float u2 = u * u; p0 = u2 * u; p1 = u2 * u2; p2 = p0 * u2; }
                    const int bi = ((a - 8 * chalf) * NDEG + dh) * VSTR + cl;
                    s_vtw[bi]            = (_Float16)(g * p0);
                    s_vtw[bi + VSTR]     = (_Float16)(g * p1);
                    s_vtw[bi + 2 * VSTR] = (_Float16)(g * p2);
                }
            }
        }
        // A-frag; tile1 t>8 reads rows 25..31 (in-slice garbage -> unread M rows)
        const half8 av = *(const half8*)(s_PM + arow * PSTR + ch * 32 + kq * 8);
        #pragma unroll
        for (int lct = 0; lct < 3; ++lct) {
            const half8 b = *(const half8*)(s_vtw + (lct * 16 + t) * VSTR + kq * 8);
            M[lct] = __builtin_amdgcn_mfma_f32_16x16x32_f16(av, b, M[lct], 0, 0, 0);
        }
    }

    // ---- M quadrant -> LDS f16 A-layout. D: col=t, row=kq*4+reg ----
    #pragma unroll
    for (int lct = 0; lct < 3; ++lct) {
        const int md = (chalf * 3 + lct) * 16 + t;
        #pragma unroll
        for (int reg = 0; reg < 4; ++reg) {
            const int lr = kq * 4 + reg;
            if (tile == 0)
                s_PM[lr * PSTR + md] = (_Float16)M[lct][reg];
            else if (lr < 9)
                s_PM[(16 + lr) * PSTR + md] = (_Float16)M[lct][reg];
        }
    }
    __syncthreads();                                        // [3] M complete

    // ---- chain2 A-frags -> regs (both tiles, all waves) ----
    half8 A0[3], A1[3];
    #pragma unroll
    for (int ks = 0; ks < 3; ++ks) {
        A0[ks] = *(const half8*)(s_PM + t * PSTR + ks * 32 + kq * 8);
        A1[ks] = *(const half8*)(s_PM + (16 + t) * PSTR + ks * 32 + kq * 8);
    }
    __syncthreads();                                        // [4] A-frags read before desc overlay

    // ---- chain 2: wave w -> nt-group g = w; fused epilogue ----
    const half8* wsv = (const half8*)ws;
    {
        const int g = wave;
        f32x4 C0g[4], C1g[4];
        #pragma unroll
        for (int j = 0; j < 4; ++j) {
            C0g[j] = (f32x4){0.f, 0.f, 0.f, 0.f};
            C1g[j] = (f32x4){0.f, 0.f, 0.f, 0.f};
        }
        #pragma unroll
        for (int j = 0; j < 4; ++j) {
            const int nt = g * 4 + j;
            half8 b0, b1, b2;
            if (USEWS) {
                b0 = wsv[(size_t)((nt * 3 + 0) * 64 + lane)];
                b1 = wsv[(size_t)((nt * 3 + 1) * 64 + lane)];
                b2 = wsv[(size_t)((nt * 3 + 2) * 64 + lane)];
            } else {
                #pragma unroll
                for (int ks = 0; ks < 3; ++ks) {
                    half8 bb;
                    #pragma unroll
                    for (int jj = 0; jj < 8; ++jj) {
                        const int k = ks * 32 + kq * 8 + jj;
                        const int a = k / NDEG, d = k % NDEG;
                        const int mm = ((a + nt) & 15) - t;
                        const float s = fmaf((float)mm, DLT, 0.5f * DLT);
                        const float z = 2.0f * 0.69314718055994530942f * Kt * s * (0.5f * DLT);
                        float val = exp2f(Kt * s * s);
                        for (int dd = 1; dd <= d; ++dd) val *= z / (float)dd;
                        bb[jj] = (_Float16)val;
                    }
                    if (ks == 0) b0 = bb; else if (ks == 1) b1 = bb; else b2 = bb;
                }
            }
            C0g[j] = __builtin_amdgcn_mfma_f32_16x16x32_f16(A0[0], b0, C0g[j], 0, 0, 0);
            C1g[j] = __builtin_amdgcn_mfma_f32_16x16x32_f16(A1[0], b0, C1g[j], 0, 0, 0);
            C0g[j] = __builtin_amdgcn_mfma_f32_16x16x32_f16(A0[1], b1, C0g[j], 0, 0, 0);
            C1g[j] = __builtin_amdgcn_mfma_f32_16x16x32_f16(A1[1], b1, C1g[j], 0, 0, 0);
            C0g[j] = __builtin_amdgcn_mfma_f32_16x16x32_f16(A0[2], b2, C0g[j], 0, 0, 0);
            C1g[j] = __builtin_amdgcn_mfma_f32_16x16x32_f16(A1[2], b2, C1g[j], 0, 0, 0);
        }
        // fused epilogue (R5-verified): desc = num/(den+eps) -> s_d[i][k][bb]
        #pragma unroll
        for (int j = 0; j < 4; ++j) {
            const int nt = g * 4 + j;
            float den[5], inv[5];
            #pragma unroll
            for (int r = 0; r < 4; ++r) den[r] = __shfl(C1g[j][r], 16 + t);
            den[4] = __shfl(C1g[j][0], 32 + t);
            #pragma unroll
            for (int r = 0; r < NRH; ++r) {
                const float x = den[r] + EPSF;
                float vv = __builtin_amdgcn_rcpf(x);
                inv[r] = vv * (2.0f - x * vv);
            }
            #pragma unroll
            for (int reg = 0; reg < 4; ++reg)
                s_d[kq * 1280 + nt * DSTR + reg * 16 + t] =
                    (_Float16)(C0g[j][reg] * inv[reg]);
            if (kq == 0) {
                #pragma unroll
                for (int reg = 0; reg < 4; ++reg)
                    s_d[reg * 1280 + nt * DSTR + 64 + t] =
                        (_Float16)(C1g[j][reg] * inv[4]);
            }
        }
    }
    __syncthreads();                                        // [5] desc complete

    // ---- phase 2: wave w -> feature i = w ----
    {
        const int i = wave;
        f32x4 Cc[5];
        #pragma unroll
        for (int tl = 0; tl < 5; ++tl) Cc[tl] = (f32x4){0.f, 0.f, 0.f, 0.f};
        #pragma unroll
        for (int ks = 0; ks < 3; ++ks) {
            const half8 a = *(const half8*)(s_d + i * 1280 + t * DSTR + ks * 32 + kq * 8);
            #pragma unroll
            for (int tl = 0; tl < 5; ++tl) {
                half8 b;
                if (USEWS) {
                    b = wsv[(size_t)((NSET_C + (i * 5 + tl) * 3 + ks) * 64 + lane)];
                } else {
                    const int cc  = tl * 16 + t;
                    const int bb0 = ks * 32 + kq * 8;
                    #pragma unroll
                    for (int j = 0; j < 8; ++j) {
                        const int bb = bb0 + j;
                        b[j] = (_Float16)((bb < NBINS) ? Wc[i * NBINS * NBINS + bb * NBINS + cc] : 0.0f);
                    }
                }
                Cc[tl] = __builtin_amdgcn_mfma_f32_16x16x32_f16(a, b, Cc[tl], 0, 0, 0);
            }
        }
        #pragma unroll
        for (int tl = 0; tl < 5; ++tl) {
            float mx = fmaxf(fmaxf(Cc[tl][0], Cc[tl][1]), fmaxf(Cc[tl][2], Cc[tl][3]));
            mx = fmaxf(mx, __shfl_xor(mx, 16));
            mx = fmaxf(mx, __shfl_xor(mx, 32));
            if (lane < 16) {
                const int cc = tl * 16 + lane;
                out[(size_t)n * 320 + i * NBINS + cc] =
                    fmaxf(mx + bcv[i * NBINS + cc], 0.0f);
            }
        }
    }
}

extern "C" void kernel_launch(void* const* d_in, const int* in_sizes, int n_in,
                              void* d_out, int out_size, void* d_ws, size_t ws_size,
                              hipStream_t stream) {
    const float* rho   = (const float*)d_in[0];
    const float* theta = (const float*)d_in[1];
    const float* feat  = (const float*)d_in[2];
    const float* mask  = (const float*)d_in[3];
    const float* mu_r  = (const float*)d_in[4];
    const float* sg_r  = (const float*)d_in[5];
    const float* mu_t  = (const float*)d_in[6];
    const float* sg_t  = (const float*)d_in[7];
    const float* W     = (const float*)d_in[8];
    const float* bconv = (const float*)d_in[9];
    float* outp = (float*)d_out;

    const int nsamp = in_sizes[0] / NVERT;
    const int useWs = (ws_size >= (size_t)WS_BYTES) ? 1 : 0;
    _Float16* wsh = (_Float16*)d_ws;

    if (useWs) {
        prep_frags<<<NSET_C + NSET_W, 64, 0, stream>>>(W, sg_t, wsh);
        masif_geo_conv<1><<<nsamp, 256, 0, stream>>>(
            rho, theta, feat, mask, mu_r, sg_r, mu_t, sg_t, W, bconv,
            wsh, nsamp, outp);
    } else {
        masif_geo_conv<0><<<nsamp, 256, 0, stream>>>(
            rho, theta, feat, mask, mu_r, sg_r, mu_t, sg_t, W, bconv,
            wsh, nsamp, outp);
    }
}